// Round 1
// baseline (802.190 us; speedup 1.0000x reference)
//
#include <hip/hip_runtime.h>
#include <math.h>

typedef unsigned int uint;
typedef unsigned short ushort;
typedef short bf16x8 __attribute__((ext_vector_type(8)));
typedef float f32x4 __attribute__((ext_vector_type(4)));

#define EPSV 1e-5f
#define SCALE 0.17677669529663687f   // 1/sqrt(32)

// param buffer offsets (bf16 elements) inside d_ws
#define OFF_WQKV 0
#define OFF_WOUT 196608
#define OFF_BQKV 262144
#define OFF_BOUT 262912
#define OFF_LNXW 263168
#define OFF_LNXB 263424
#define OFF_LNRW 263680
#define OFF_LNRB 263936

// LDS plan (40960 B total -> 4 blocks/CU = 16 waves/CU):
//   stage  ushort[64][264] = 33792 B at offset 0 (LN staging, later ao/out staging)
//   per-head double buffer: buf{0,1} at 0 / 14848, each:
//        qh ushort[64][40]  (5120 B)  A-layout q for this head
//        kh ushort[64][40]  (5120 B)
//        vh ushort[32][72]  (4608 B)  v transposed [ch][tok]
//   Pw  4 x ushort[16][72] = 9216 B at offset 29696 (per-wave P transpose scratch)
#define BUFSZ 14848
#define L_P   29696
#define LDS_TOTAL 40960

__device__ __forceinline__ float bf2f(ushort u) {
    union { float f; uint i; } z; z.i = ((uint)u) << 16; return z.f;
}
__device__ __forceinline__ ushort f2bf(float f) {
    union { float f; uint i; } z; z.f = f;
    uint i = z.i;
    return (ushort)((i + 0x7FFFu + ((i >> 16) & 1u)) >> 16);
}
__device__ __forceinline__ uint pack2(float a, float b) {
    return (uint)f2bf(a) | ((uint)f2bf(b) << 16);
}

__device__ __forceinline__ bool detect_f32(const uint* __restrict__ xw) {
    int cnt = 0;
    #pragma unroll
    for (int i = 0; i < 64; ++i) {
        uint e = (xw[i] >> 7) & 0xFFu;
        cnt += (e >= 0x60u && e <= 0x8Au) ? 1 : 0;
    }
    return cnt < 32;
}

// ---------------------------------------------------------------------------
// Param conversion (unchanged).
// ---------------------------------------------------------------------------
__global__ __launch_bounds__(256) void kParams(
    const void* __restrict__ x,
    const void* __restrict__ lnxw, const void* __restrict__ lnxb,
    const void* __restrict__ lnrw, const void* __restrict__ lnrb,
    const void* __restrict__ wqkv, const void* __restrict__ bqkv,
    const void* __restrict__ wout, const void* __restrict__ bout,
    ushort* __restrict__ pb)
{
    const bool f32 = detect_f32((const uint*)x);
    const int blk = blockIdx.x, tid = threadIdx.x;
    const void* src; int si, doff;
    if (blk < 768)        { src = wqkv; si = blk * 256 + tid;          doff = OFF_WQKV; }
    else if (blk < 1024)  { src = wout; si = (blk - 768) * 256 + tid;  doff = OFF_WOUT; }
    else if (blk < 1027)  { src = bqkv; si = (blk - 1024) * 256 + tid; doff = OFF_BQKV; }
    else if (blk == 1027) { src = bout; si = tid; doff = OFF_BOUT; }
    else if (blk == 1028) { src = lnxw; si = tid; doff = OFF_LNXW; }
    else if (blk == 1029) { src = lnxb; si = tid; doff = OFF_LNXB; }
    else if (blk == 1030) { src = lnrw; si = tid; doff = OFF_LNRW; }
    else                  { src = lnrb; si = tid; doff = OFF_LNRB; }
    pb[doff + si] = f32 ? f2bf(((const float*)src)[si]) : ((const ushort*)src)[si];
}

// ---------------------------------------------------------------------------
// Per-head projection: q_h -> qh (A-layout), k_h -> kh, v_h -> vh (transposed).
// B-frag loads grouped by 4 to bound register pressure (96 persistent regs).
// ---------------------------------------------------------------------------
__device__ __forceinline__ void projHead(
    const ushort* __restrict__ pb, char* __restrict__ buf,
    const bf16x8 (&ax)[8], const bf16x8 (&ar)[8],
    const int h, const int wave, const int col, const int quad)
{
    ushort (*qh)[40] = (ushort (*)[40])(buf);
    ushort (*kh)[40] = (ushort (*)[40])(buf + 5120);
    ushort (*vh)[72] = (ushort (*)[72])(buf + 10240);
    const ushort* wq = pb + OFF_WQKV;

    #pragma unroll
    for (int tt = 0; tt < 2; ++tt) {
        const int ch = h * 32 + tt * 16 + col;
        // ---- q (from LN(x) frags) ----
        {
            const bf16x8* bp = (const bf16x8*)(wq + (size_t)ch * 256 + quad * 8);
            f32x4 acc = {0.f, 0.f, 0.f, 0.f};
            #pragma unroll
            for (int g = 0; g < 2; ++g) {
                bf16x8 bb[4];
                #pragma unroll
                for (int k2 = 0; k2 < 4; ++k2) bb[k2] = bp[(g * 4 + k2) * 4];
                #pragma unroll
                for (int k2 = 0; k2 < 4; ++k2)
                    acc = __builtin_amdgcn_mfma_f32_16x16x32_bf16(ax[g * 4 + k2], bb[k2], acc, 0, 0, 0);
            }
            const float bias = bf2f(pb[OFF_BQKV + ch]);
            #pragma unroll
            for (int rg = 0; rg < 4; ++rg)
                qh[wave * 16 + quad * 4 + rg][tt * 16 + col] = f2bf((acc[rg] + bias) * SCALE);
        }
        // ---- k (from LN(r) frags) ----
        {
            const int wrow = 256 + ch;
            const bf16x8* bp = (const bf16x8*)(wq + (size_t)wrow * 256 + quad * 8);
            f32x4 acc = {0.f, 0.f, 0.f, 0.f};
            #pragma unroll
            for (int g = 0; g < 2; ++g) {
                bf16x8 bb[4];
                #pragma unroll
                for (int k2 = 0; k2 < 4; ++k2) bb[k2] = bp[(g * 4 + k2) * 4];
                #pragma unroll
                for (int k2 = 0; k2 < 4; ++k2)
                    acc = __builtin_amdgcn_mfma_f32_16x16x32_bf16(ar[g * 4 + k2], bb[k2], acc, 0, 0, 0);
            }
            const float bias = bf2f(pb[OFF_BQKV + wrow]);
            #pragma unroll
            for (int rg = 0; rg < 4; ++rg)
                kh[wave * 16 + quad * 4 + rg][tt * 16 + col] = f2bf(acc[rg] + bias);
        }
        // ---- v (from LN(r) frags), transposed to [ch][tok] ----
        {
            const int wrow = 512 + ch;
            const bf16x8* bp = (const bf16x8*)(wq + (size_t)wrow * 256 + quad * 8);
            f32x4 acc = {0.f, 0.f, 0.f, 0.f};
            #pragma unroll
            for (int g = 0; g < 2; ++g) {
                bf16x8 bb[4];
                #pragma unroll
                for (int k2 = 0; k2 < 4; ++k2) bb[k2] = bp[(g * 4 + k2) * 4];
                #pragma unroll
                for (int k2 = 0; k2 < 4; ++k2)
                    acc = __builtin_amdgcn_mfma_f32_16x16x32_bf16(ar[g * 4 + k2], bb[k2], acc, 0, 0, 0);
            }
            const float bias = bf2f(pb[OFF_BQKV + wrow]);
            uint2 pv;
            pv.x = pack2(acc[0] + bias, acc[1] + bias);
            pv.y = pack2(acc[2] + bias, acc[3] + bias);
            *(uint2*)&vh[tt * 16 + col][wave * 16 + quad * 4] = pv;
        }
    }
}

// ---------------------------------------------------------------------------
// Per-head attention: QK^T (K=32), wave-parallel softmax, PV. ao -> regs.
// ---------------------------------------------------------------------------
__device__ __forceinline__ void attHead(
    char* __restrict__ buf, ushort (*Pw)[72], uint (&aopk)[16][2],
    const int h, const int wave, const int col, const int quad)
{
    ushort (*qh)[40] = (ushort (*)[40])(buf);
    ushort (*kh)[40] = (ushort (*)[40])(buf + 5120);
    ushort (*vh)[72] = (ushort (*)[72])(buf + 10240);

    const bf16x8 qa = *(const bf16x8*)&qh[wave * 16 + col][quad * 8];
    f32x4 s[4];
    #pragma unroll
    for (int nt = 0; nt < 4; ++nt) {
        const bf16x8 kb = *(const bf16x8*)&kh[nt * 16 + col][quad * 8];
        f32x4 z = {0.f, 0.f, 0.f, 0.f};
        s[nt] = __builtin_amdgcn_mfma_f32_16x16x32_bf16(qa, kb, z, 0, 0, 0);
    }
    #pragma unroll
    for (int rg = 0; rg < 4; ++rg) {
        float m = fmaxf(fmaxf(s[0][rg], s[1][rg]), fmaxf(s[2][rg], s[3][rg]));
        m = fmaxf(m, __shfl_xor(m, 1));
        m = fmaxf(m, __shfl_xor(m, 2));
        m = fmaxf(m, __shfl_xor(m, 4));
        m = fmaxf(m, __shfl_xor(m, 8));
        float p0 = __expf(s[0][rg] - m);
        float p1 = __expf(s[1][rg] - m);
        float p2 = __expf(s[2][rg] - m);
        float p3 = __expf(s[3][rg] - m);
        float sm = p0 + p1 + p2 + p3;
        sm += __shfl_xor(sm, 1);
        sm += __shfl_xor(sm, 2);
        sm += __shfl_xor(sm, 4);
        sm += __shfl_xor(sm, 8);
        const float inv = 1.f / sm;
        s[0][rg] = p0 * inv; s[1][rg] = p1 * inv;
        s[2][rg] = p2 * inv; s[3][rg] = p3 * inv;
    }
    #pragma unroll
    for (int nt = 0; nt < 4; ++nt)
        #pragma unroll
        for (int rg = 0; rg < 4; ++rg)
            Pw[quad * 4 + rg][nt * 16 + col] = f2bf(s[nt][rg]);
    const bf16x8 pa0 = *(const bf16x8*)&Pw[col][quad * 8];
    const bf16x8 pa1 = *(const bf16x8*)&Pw[col][32 + quad * 8];
    #pragma unroll
    for (int n2 = 0; n2 < 2; ++n2) {
        const bf16x8 bv0 = *(const bf16x8*)&vh[n2 * 16 + col][quad * 8];
        const bf16x8 bv1 = *(const bf16x8*)&vh[n2 * 16 + col][32 + quad * 8];
        f32x4 acc = {0.f, 0.f, 0.f, 0.f};
        acc = __builtin_amdgcn_mfma_f32_16x16x32_bf16(pa0, bv0, acc, 0, 0, 0);
        acc = __builtin_amdgcn_mfma_f32_16x16x32_bf16(pa1, bv1, acc, 0, 0, 0);
        aopk[2 * h + n2][0] = pack2(acc[0], acc[1]);
        aopk[2 * h + n2][1] = pack2(acc[2], acc[3]);
    }
}

// ---------------------------------------------------------------------------
// Fused per-window kernel, per-head streamed, 40960 B LDS -> 4 blocks/CU.
// ---------------------------------------------------------------------------
__global__ __launch_bounds__(256, 4) void kMain(
    const void* __restrict__ xv, const void* __restrict__ rv,
    const ushort* __restrict__ pb, void* __restrict__ outv)
{
    extern __shared__ char smem[];
    ushort (*stage)[264] = (ushort (*)[264])smem;

    const bool f32 = detect_f32((const uint*)xv);
    const int w = blockIdx.x, b = w >> 8, hw = (w >> 4) & 15, ww = w & 15;
    const int tid = threadIdx.x;
    const int lane = tid & 63, wave = tid >> 6;
    const int col = lane & 15, quad = lane >> 4;
    ushort (*Pw)[72] = (ushort (*)[72])(smem + L_P + wave * 2304);

    // ---- Phase 1: LN both tensors, sequentially through one stage buffer ----
    bf16x8 ax[8], ar[8];
    {
        const int row = tid >> 2, l4 = tid & 3;
        const int pi = row >> 3, pj = row & 7;
        const size_t gidx = ((size_t)((b * 128 + hw * 8 + pi) * 128 + ww * 8 + pj)) * 256
                          + (size_t)(l4 * 64);
        #pragma unroll
        for (int t = 0; t < 2; ++t) {
            const void* src = t ? rv : xv;
            const ushort* lw = pb + (t ? OFF_LNRW : OFF_LNXW);
            const ushort* lb = pb + (t ? OFF_LNRB : OFF_LNXB);

            float vals[64];
            if (f32) {
                const float4* g = (const float4*)((const float*)src + gidx);
                #pragma unroll
                for (int it = 0; it < 16; ++it) {
                    float4 q = g[it];
                    vals[it * 4 + 0] = q.x; vals[it * 4 + 1] = q.y;
                    vals[it * 4 + 2] = q.z; vals[it * 4 + 3] = q.w;
                }
            } else {
                const uint4* g = (const uint4*)((const ushort*)src + gidx);
                #pragma unroll
                for (int it = 0; it < 8; ++it) {
                    uint4 q = g[it];
                    uint u[4] = {q.x, q.y, q.z, q.w};
                    #pragma unroll
                    for (int e = 0; e < 4; ++e) {
                        vals[it * 8 + e * 2]     = bf2f((ushort)(u[e] & 0xffff));
                        vals[it * 8 + e * 2 + 1] = bf2f((ushort)(u[e] >> 16));
                    }
                }
            }
            float s0 = 0.f, s1 = 0.f;
            #pragma unroll
            for (int c = 0; c < 64; ++c) { s0 += vals[c]; s1 += vals[c] * vals[c]; }
            s0 += __shfl_xor(s0, 1); s1 += __shfl_xor(s1, 1);
            s0 += __shfl_xor(s0, 2); s1 += __shfl_xor(s1, 2);
            const float mean = s0 * (1.f / 256.f);
            const float var  = s1 * (1.f / 256.f) - mean * mean;
            const float rs   = rsqrtf(var + EPSV);
            #pragma unroll
            for (int c = 0; c < 64; c += 2) {
                const int ch = l4 * 64 + c;
                float a = (vals[c]     - mean) * rs * bf2f(lw[ch])     + bf2f(lb[ch]);
                float d = (vals[c + 1] - mean) * rs * bf2f(lw[ch + 1]) + bf2f(lb[ch + 1]);
                *(uint*)&stage[row][ch] = (uint)f2bf(a) | ((uint)f2bf(d) << 16);
            }
            __syncthreads();
            #pragma unroll
            for (int ks = 0; ks < 8; ++ks) {
                bf16x8 f = *(const bf16x8*)&stage[wave * 16 + col][ks * 32 + quad * 8];
                if (t == 0) ax[ks] = f; else ar[ks] = f;
            }
            __syncthreads();   // stage free for per-head buffers / next tensor
        }
    }

    // ---- Phase 2+3: per-head QKV projection + attention, double-buffered ----
    uint aopk[16][2];
    projHead(pb, smem, ax, ar, 0, wave, col, quad);
    __syncthreads();
    #pragma unroll
    for (int h = 0; h < 8; ++h) {
        char* cur = smem + (h & 1) * BUFSZ;
        char* nxt = smem + ((h & 1) ^ 1) * BUFSZ;
        if (h < 7) projHead(pb, nxt, ax, ar, h + 1, wave, col, quad);
        attHead(cur, Pw, aopk, h, wave, col, quad);
        __syncthreads();
    }

    // ---- Phase 4: out-projection + coalesced store (stage buffer reused) ----
    {
        // ao C-layout -> stage band (wave-local) -> A-frags
        #pragma unroll
        for (int t = 0; t < 16; ++t) {
            const uint lo = aopk[t][0], hi = aopk[t][1];
            stage[wave * 16 + quad * 4 + 0][t * 16 + col] = (ushort)(lo & 0xffff);
            stage[wave * 16 + quad * 4 + 1][t * 16 + col] = (ushort)(lo >> 16);
            stage[wave * 16 + quad * 4 + 2][t * 16 + col] = (ushort)(hi & 0xffff);
            stage[wave * 16 + quad * 4 + 3][t * 16 + col] = (ushort)(hi >> 16);
        }
        bf16x8 af[8];
        #pragma unroll
        for (int ks = 0; ks < 8; ++ks)
            af[ks] = *(const bf16x8*)&stage[wave * 16 + col][ks * 32 + quad * 8];

        const ushort* wo = pb + OFF_WOUT;
        if (!f32) {
            #pragma unroll 2
            for (int ntl = 0; ntl < 16; ++ntl) {
                const int orow = ntl * 16 + col;
                const bf16x8* bp = (const bf16x8*)(wo + (size_t)orow * 256 + quad * 8);
                f32x4 acc = {0.f, 0.f, 0.f, 0.f};
                #pragma unroll
                for (int g = 0; g < 2; ++g) {
                    bf16x8 bb[4];
                    #pragma unroll
                    for (int k2 = 0; k2 < 4; ++k2) bb[k2] = bp[(g * 4 + k2) * 4];
                    #pragma unroll
                    for (int k2 = 0; k2 < 4; ++k2)
                        acc = __builtin_amdgcn_mfma_f32_16x16x32_bf16(af[g * 4 + k2], bb[k2], acc, 0, 0, 0);
                }
                const float bias = bf2f(pb[OFF_BOUT + orow]);
                #pragma unroll
                for (int rg = 0; rg < 4; ++rg)
                    stage[wave * 16 + quad * 4 + rg][orow] = f2bf(acc[rg] + bias);
            }
            // wave-local coalesced dump: 16 rows x 512B per wave
            const int row = wave * 16 + (lane >> 2), l4 = lane & 3;
            const size_t gbase = ((size_t)((b * 128 + hw * 8 + (row >> 3)) * 128
                                 + ww * 8 + (row & 7))) * 256 + (size_t)(l4 * 64);
            #pragma unroll
            for (int e = 0; e < 8; ++e) {
                uint4 vvv = *(const uint4*)&stage[row][l4 * 64 + e * 8];
                *(uint4*)((ushort*)outv + gbase + e * 8) = vvv;
            }
        } else {
            // f32 output: two half-channel passes staged as float through LDS,
            // dumped as float4 (row stride 132 floats = 528 B, same band bytes).
            float (*vof)[132] = (float (*)[132])smem;
            #pragma unroll
            for (int half = 0; half < 2; ++half) {
                #pragma unroll
                for (int nn = 0; nn < 8; ++nn) {
                    const int ntl = half * 8 + nn;
                    const int orow = ntl * 16 + col;
                    const bf16x8* bp = (const bf16x8*)(wo + (size_t)orow * 256 + quad * 8);
                    f32x4 acc = {0.f, 0.f, 0.f, 0.f};
                    #pragma unroll
                    for (int g = 0; g < 2; ++g) {
                        bf16x8 bb[4];
                        #pragma unroll
                        for (int k2 = 0; k2 < 4; ++k2) bb[k2] = bp[(g * 4 + k2) * 4];
                        #pragma unroll
                        for (int k2 = 0; k2 < 4; ++k2)
                            acc = __builtin_amdgcn_mfma_f32_16x16x32_bf16(af[g * 4 + k2], bb[k2], acc, 0, 0, 0);
                    }
                    const float bias = bf2f(pb[OFF_BOUT + orow]);
                    #pragma unroll
                    for (int rg = 0; rg < 4; ++rg)
                        vof[wave * 16 + quad * 4 + rg][nn * 16 + col] = acc[rg] + bias;
                }
                const int row = wave * 16 + (lane >> 2), l4 = lane & 3;
                const size_t gb = ((size_t)((b * 128 + hw * 8 + (row >> 3)) * 128
                                  + ww * 8 + (row & 7))) * 256 + (size_t)(half * 128);
                #pragma unroll
                for (int e = 0; e < 8; ++e) {
                    float4 vv = *(const float4*)&vof[row][e * 16 + l4 * 4];
                    *(float4*)((float*)outv + gb + e * 16 + l4 * 4) = vv;
                }
            }
        }
    }
}

// ---------------------------------------------------------------------------
extern "C" void kernel_launch(void* const* d_in, const int* in_sizes, int n_in,
                              void* d_out, int out_size, void* d_ws, size_t ws_size,
                              hipStream_t stream)
{
    const void* x    = d_in[0];
    const void* r    = d_in[1];
    const void* lnxw = d_in[2];
    const void* lnxb = d_in[3];
    const void* lnrw = d_in[4];
    const void* lnrb = d_in[5];
    const void* wqkv = d_in[6];
    const void* bqkv = d_in[7];
    const void* wout = d_in[8];
    const void* bout = d_in[9];

    ushort* pb = (ushort*)d_ws;   // 264192 bf16 elements = 516 KB

    kParams<<<1032, 256, 0, stream>>>(x, lnxw, lnxb, lnrw, lnrb,
                                      wqkv, bqkv, wout, bout, pb);

    (void)hipFuncSetAttribute((const void*)kMain,
                              hipFuncAttributeMaxDynamicSharedMemorySize, LDS_TOTAL);
    kMain<<<2048, 256, LDS_TOTAL, stream>>>(x, r, pb, d_out);
}

// Round 3
// 799.982 us; speedup vs baseline: 1.0028x; 1.0028x over previous
//
#include <hip/hip_runtime.h>
#include <math.h>

typedef unsigned int uint;
typedef unsigned short ushort;
typedef short bf16x8 __attribute__((ext_vector_type(8)));
typedef float f32x4 __attribute__((ext_vector_type(4)));

#define EPSV 1e-5f
#define SCALE 0.17677669529663687f   // 1/sqrt(32)

// param buffer offsets (bf16 elements) inside d_ws
#define OFF_WQKV 0
#define OFF_WOUT 196608
#define OFF_BQKV 262144
#define OFF_BOUT 262912
#define OFF_LNXW 263168
#define OFF_LNXB 263424
#define OFF_LNRW 263680
#define OFF_LNRB 263936

// LDS plan (72704 B -> 2 blocks/CU; round-1 measured occupancy is NOT the lever,
// so we spend LDS to keep the head loop ROLLED (small I$ footprint) and all
// per-head state addressable by runtime h):
//   A   ushort[64][264] = 33792 B @ 0      LN staging -> ao accum -> out staging
//   B0  14848 B @ 33792   head buf 0: qh[64][40] | kh[64][40] | vh[32][72]
//   B1  14848 B @ 48640   head buf 1
//   Pw  4 x ushort[16][72] = 9216 B @ 63488  per-wave P transpose scratch
#define L_A   0
#define L_B0  33792
#define L_B1  48640
#define L_PW  63488
#define BUFSZ 14848
#define LDS_TOTAL 72704

__device__ __forceinline__ float bf2f(ushort u) {
    union { float f; uint i; } z; z.i = ((uint)u) << 16; return z.f;
}
__device__ __forceinline__ ushort f2bf(float f) {
    union { float f; uint i; } z; z.f = f;
    uint i = z.i;
    return (ushort)((i + 0x7FFFu + ((i >> 16) & 1u)) >> 16);
}
__device__ __forceinline__ uint pack2(float a, float b) {
    return (uint)f2bf(a) | ((uint)f2bf(b) << 16);
}

// wave-parallel f32 detection: one load per lane + ballot (was 64 loads/thread)
__device__ __forceinline__ bool detect_f32_wave(const uint* __restrict__ xw, int lane) {
    const uint e = (xw[lane] >> 7) & 0xFFu;
    const int pred = (e >= 0x60u && e <= 0x8Au) ? 1 : 0;
    const unsigned long long m = __ballot(pred);
    return __popcll(m) < 32;
}

// ---------------------------------------------------------------------------
// Param conversion.
// ---------------------------------------------------------------------------
__global__ __launch_bounds__(256) void kParams(
    const void* __restrict__ x,
    const void* __restrict__ lnxw, const void* __restrict__ lnxb,
    const void* __restrict__ lnrw, const void* __restrict__ lnrb,
    const void* __restrict__ wqkv, const void* __restrict__ bqkv,
    const void* __restrict__ wout, const void* __restrict__ bout,
    ushort* __restrict__ pb)
{
    const bool f32 = detect_f32_wave((const uint*)x, threadIdx.x & 63);
    const int blk = blockIdx.x, tid = threadIdx.x;
    const void* src; int si, doff;
    if (blk < 768)        { src = wqkv; si = blk * 256 + tid;          doff = OFF_WQKV; }
    else if (blk < 1024)  { src = wout; si = (blk - 768) * 256 + tid;  doff = OFF_WOUT; }
    else if (blk < 1027)  { src = bqkv; si = (blk - 1024) * 256 + tid; doff = OFF_BQKV; }
    else if (blk == 1027) { src = bout; si = tid; doff = OFF_BOUT; }
    else if (blk == 1028) { src = lnxw; si = tid; doff = OFF_LNXW; }
    else if (blk == 1029) { src = lnxb; si = tid; doff = OFF_LNXB; }
    else if (blk == 1030) { src = lnrw; si = tid; doff = OFF_LNRW; }
    else                  { src = lnrb; si = tid; doff = OFF_LNRB; }
    pb[doff + si] = f32 ? f2bf(((const float*)src)[si]) : ((const ushort*)src)[si];
}

// ---------------------------------------------------------------------------
// Per-head projection (runtime h): q_h -> qh, k_h -> kh, v_h -> vh (transposed).
// ---------------------------------------------------------------------------
__device__ __forceinline__ void projHead(
    const ushort* __restrict__ pb, char* __restrict__ buf,
    const bf16x8 (&ax)[8], const bf16x8 (&ar)[8],
    const int h, const int wave, const int col, const int quad)
{
    ushort (*qh)[40] = (ushort (*)[40])(buf);
    ushort (*kh)[40] = (ushort (*)[40])(buf + 5120);
    ushort (*vh)[72] = (ushort (*)[72])(buf + 10240);
    const ushort* wq = pb + OFF_WQKV;

    #pragma unroll 1
    for (int tt = 0; tt < 2; ++tt) {
        const int ch = h * 32 + tt * 16 + col;
        // ---- q (from LN(x) frags) ----
        {
            const bf16x8* bp = (const bf16x8*)(wq + (size_t)ch * 256 + quad * 8);
            bf16x8 bb[8];
            #pragma unroll
            for (int ks = 0; ks < 8; ++ks) bb[ks] = bp[ks * 4];
            f32x4 acc = {0.f, 0.f, 0.f, 0.f};
            #pragma unroll
            for (int ks = 0; ks < 8; ++ks)
                acc = __builtin_amdgcn_mfma_f32_16x16x32_bf16(ax[ks], bb[ks], acc, 0, 0, 0);
            const float bias = bf2f(pb[OFF_BQKV + ch]);
            #pragma unroll
            for (int rg = 0; rg < 4; ++rg)
                qh[wave * 16 + quad * 4 + rg][tt * 16 + col] = f2bf((acc[rg] + bias) * SCALE);
        }
        // ---- k (from LN(r) frags) ----
        {
            const int wrow = 256 + ch;
            const bf16x8* bp = (const bf16x8*)(wq + (size_t)wrow * 256 + quad * 8);
            bf16x8 bb[8];
            #pragma unroll
            for (int ks = 0; ks < 8; ++ks) bb[ks] = bp[ks * 4];
            f32x4 acc = {0.f, 0.f, 0.f, 0.f};
            #pragma unroll
            for (int ks = 0; ks < 8; ++ks)
                acc = __builtin_amdgcn_mfma_f32_16x16x32_bf16(ar[ks], bb[ks], acc, 0, 0, 0);
            const float bias = bf2f(pb[OFF_BQKV + wrow]);
            #pragma unroll
            for (int rg = 0; rg < 4; ++rg)
                kh[wave * 16 + quad * 4 + rg][tt * 16 + col] = f2bf(acc[rg] + bias);
        }
        // ---- v (from LN(r) frags), transposed to [ch][tok] ----
        {
            const int wrow = 512 + ch;
            const bf16x8* bp = (const bf16x8*)(wq + (size_t)wrow * 256 + quad * 8);
            bf16x8 bb[8];
            #pragma unroll
            for (int ks = 0; ks < 8; ++ks) bb[ks] = bp[ks * 4];
            f32x4 acc = {0.f, 0.f, 0.f, 0.f};
            #pragma unroll
            for (int ks = 0; ks < 8; ++ks)
                acc = __builtin_amdgcn_mfma_f32_16x16x32_bf16(ar[ks], bb[ks], acc, 0, 0, 0);
            const float bias = bf2f(pb[OFF_BQKV + wrow]);
            uint2 pv;
            pv.x = pack2(acc[0] + bias, acc[1] + bias);
            pv.y = pack2(acc[2] + bias, acc[3] + bias);
            *(uint2*)&vh[tt * 16 + col][wave * 16 + quad * 4] = pv;
        }
    }
}

// ---------------------------------------------------------------------------
// Per-head attention (runtime h): QK^T, wave-parallel softmax, PV.
// Output written C-layout directly into the wave-local rows of ao (LDS).
// ---------------------------------------------------------------------------
__device__ __forceinline__ void attHead(
    char* __restrict__ buf, ushort (*Pw)[72], ushort (*ao)[264],
    const int h, const int wave, const int col, const int quad)
{
    ushort (*qh)[40] = (ushort (*)[40])(buf);
    ushort (*kh)[40] = (ushort (*)[40])(buf + 5120);
    ushort (*vh)[72] = (ushort (*)[72])(buf + 10240);

    const bf16x8 qa = *(const bf16x8*)&qh[wave * 16 + col][quad * 8];
    f32x4 s[4];
    #pragma unroll
    for (int nt = 0; nt < 4; ++nt) {
        const bf16x8 kb = *(const bf16x8*)&kh[nt * 16 + col][quad * 8];
        f32x4 z = {0.f, 0.f, 0.f, 0.f};
        s[nt] = __builtin_amdgcn_mfma_f32_16x16x32_bf16(qa, kb, z, 0, 0, 0);
    }
    #pragma unroll
    for (int rg = 0; rg < 4; ++rg) {
        float m = fmaxf(fmaxf(s[0][rg], s[1][rg]), fmaxf(s[2][rg], s[3][rg]));
        m = fmaxf(m, __shfl_xor(m, 1));
        m = fmaxf(m, __shfl_xor(m, 2));
        m = fmaxf(m, __shfl_xor(m, 4));
        m = fmaxf(m, __shfl_xor(m, 8));
        float p0 = __expf(s[0][rg] - m);
        float p1 = __expf(s[1][rg] - m);
        float p2 = __expf(s[2][rg] - m);
        float p3 = __expf(s[3][rg] - m);
        float sm = p0 + p1 + p2 + p3;
        sm += __shfl_xor(sm, 1);
        sm += __shfl_xor(sm, 2);
        sm += __shfl_xor(sm, 4);
        sm += __shfl_xor(sm, 8);
        const float inv = 1.f / sm;
        s[0][rg] = p0 * inv; s[1][rg] = p1 * inv;
        s[2][rg] = p2 * inv; s[3][rg] = p3 * inv;
    }
    #pragma unroll
    for (int nt = 0; nt < 4; ++nt)
        #pragma unroll
        for (int rg = 0; rg < 4; ++rg)
            Pw[quad * 4 + rg][nt * 16 + col] = f2bf(s[nt][rg]);
    const bf16x8 pa0 = *(const bf16x8*)&Pw[col][quad * 8];
    const bf16x8 pa1 = *(const bf16x8*)&Pw[col][32 + quad * 8];
    #pragma unroll
    for (int n2 = 0; n2 < 2; ++n2) {
        const bf16x8 bv0 = *(const bf16x8*)&vh[n2 * 16 + col][quad * 8];
        const bf16x8 bv1 = *(const bf16x8*)&vh[n2 * 16 + col][32 + quad * 8];
        f32x4 acc = {0.f, 0.f, 0.f, 0.f};
        acc = __builtin_amdgcn_mfma_f32_16x16x32_bf16(pa0, bv0, acc, 0, 0, 0);
        acc = __builtin_amdgcn_mfma_f32_16x16x32_bf16(pa1, bv1, acc, 0, 0, 0);
        #pragma unroll
        for (int rg = 0; rg < 4; ++rg)
            ao[wave * 16 + quad * 4 + rg][(2 * h + n2) * 16 + col] = f2bf(acc[rg]);
    }
}

// ---------------------------------------------------------------------------
// Fused per-window kernel: rolled head loop (small I$), ao through LDS.
// ---------------------------------------------------------------------------
__global__ __launch_bounds__(256, 2) void kMain(
    const void* __restrict__ xv, const void* __restrict__ rv,
    const ushort* __restrict__ pb, void* __restrict__ outv)
{
    extern __shared__ char smem[];
    ushort (*A)[264] = (ushort (*)[264])(smem + L_A);

    const int tid = threadIdx.x;
    const int lane = tid & 63, wave = tid >> 6;
    const int col = lane & 15, quad = lane >> 4;
    const bool f32 = detect_f32_wave((const uint*)xv, lane);
    const int w = blockIdx.x, b = w >> 8, hw = (w >> 4) & 15, ww = w & 15;
    ushort (*Pw)[72] = (ushort (*)[72])(smem + L_PW + wave * 2304);

    // ---- Phase 1: LN both tensors through region A. 8 threads/token,
    //      2 token-passes (vals[32] keeps peak register pressure low). ----
    bf16x8 ax[8], ar[8];
    {
        const int l8 = tid & 7, trow = tid >> 3;
        #pragma unroll 1
        for (int t = 0; t < 2; ++t) {
            const void* src = t ? rv : xv;
            const ushort* lw = pb + (t ? OFF_LNRW : OFF_LNXW);
            const ushort* lb = pb + (t ? OFF_LNRB : OFF_LNXB);
            #pragma unroll 1
            for (int p = 0; p < 2; ++p) {
                const int row = p * 32 + trow;
                const int pi = row >> 3, pj = row & 7;
                const size_t gidx = ((size_t)((b * 128 + hw * 8 + pi) * 128 + ww * 8 + pj)) * 256
                                  + (size_t)(l8 * 32);
                float vals[32];
                if (f32) {
                    const float4* g = (const float4*)((const float*)src + gidx);
                    #pragma unroll
                    for (int it = 0; it < 8; ++it) {
                        float4 q = g[it];
                        vals[it * 4 + 0] = q.x; vals[it * 4 + 1] = q.y;
                        vals[it * 4 + 2] = q.z; vals[it * 4 + 3] = q.w;
                    }
                } else {
                    const uint4* g = (const uint4*)((const ushort*)src + gidx);
                    #pragma unroll
                    for (int it = 0; it < 4; ++it) {
                        uint4 q = g[it];
                        uint u[4] = {q.x, q.y, q.z, q.w};
                        #pragma unroll
                        for (int e = 0; e < 4; ++e) {
                            vals[it * 8 + e * 2]     = bf2f((ushort)(u[e] & 0xffff));
                            vals[it * 8 + e * 2 + 1] = bf2f((ushort)(u[e] >> 16));
                        }
                    }
                }
                float s0 = 0.f, s1 = 0.f;
                #pragma unroll
                for (int c = 0; c < 32; ++c) { s0 += vals[c]; s1 += vals[c] * vals[c]; }
                s0 += __shfl_xor(s0, 1); s1 += __shfl_xor(s1, 1);
                s0 += __shfl_xor(s0, 2); s1 += __shfl_xor(s1, 2);
                s0 += __shfl_xor(s0, 4); s1 += __shfl_xor(s1, 4);
                const float mean = s0 * (1.f / 256.f);
                const float var  = s1 * (1.f / 256.f) - mean * mean;
                const float rs   = rsqrtf(var + EPSV);
                #pragma unroll
                for (int c = 0; c < 32; c += 2) {
                    const int ch = l8 * 32 + c;
                    float a0 = (vals[c]     - mean) * rs * bf2f(lw[ch])     + bf2f(lb[ch]);
                    float a1 = (vals[c + 1] - mean) * rs * bf2f(lw[ch + 1]) + bf2f(lb[ch + 1]);
                    *(uint*)&A[row][ch] = pack2(a0, a1);
                }
            }
            __syncthreads();
            #pragma unroll
            for (int ks = 0; ks < 8; ++ks) {
                bf16x8 f = *(const bf16x8*)&A[wave * 16 + col][ks * 32 + quad * 8];
                if (t == 0) ax[ks] = f; else ar[ks] = f;
            }
            __syncthreads();   // A free (next tensor / ao)
        }
    }

    // ---- Phase 2+3: rolled per-head loop, double-buffered head state ----
    projHead(pb, smem + L_B0, ax, ar, 0, wave, col, quad);
    __syncthreads();
    #pragma unroll 1
    for (int h = 0; h < 8; ++h) {
        char* cur = smem + ((h & 1) ? L_B1 : L_B0);
        char* nxt = smem + ((h & 1) ? L_B0 : L_B1);
        if (h < 7) projHead(pb, nxt, ax, ar, h + 1, wave, col, quad);
        attHead(cur, Pw, A, h, wave, col, quad);
        __syncthreads();
    }

    // ---- Phase 4: out-projection from ao (region A) + coalesced store.
    //      ao rows and out-staging rows are wave-local -> no extra barrier. ----
    {
        bf16x8 af[8];
        #pragma unroll
        for (int ks = 0; ks < 8; ++ks)
            af[ks] = *(const bf16x8*)&A[wave * 16 + col][ks * 32 + quad * 8];

        const ushort* wo = pb + OFF_WOUT;
        if (!f32) {
            #pragma unroll 2
            for (int ntl = 0; ntl < 16; ++ntl) {
                const int orow = ntl * 16 + col;
                const bf16x8* bp = (const bf16x8*)(wo + (size_t)orow * 256 + quad * 8);
                bf16x8 bb[8];
                #pragma unroll
                for (int ks = 0; ks < 8; ++ks) bb[ks] = bp[ks * 4];
                f32x4 acc = {0.f, 0.f, 0.f, 0.f};
                #pragma unroll
                for (int ks = 0; ks < 8; ++ks)
                    acc = __builtin_amdgcn_mfma_f32_16x16x32_bf16(af[ks], bb[ks], acc, 0, 0, 0);
                const float bias = bf2f(pb[OFF_BOUT + orow]);
                #pragma unroll
                for (int rg = 0; rg < 4; ++rg)
                    A[wave * 16 + quad * 4 + rg][orow] = f2bf(acc[rg] + bias);
            }
            const int row = wave * 16 + (lane >> 2), l4 = lane & 3;
            const size_t gbase = ((size_t)((b * 128 + hw * 8 + (row >> 3)) * 128
                                 + ww * 8 + (row & 7))) * 256 + (size_t)(l4 * 64);
            #pragma unroll
            for (int e = 0; e < 8; ++e) {
                uint4 vvv = *(const uint4*)&A[row][l4 * 64 + e * 8];
                *(uint4*)((ushort*)outv + gbase + e * 8) = vvv;
            }
        } else {
            // f32 output: two half-channel passes staged as f32 in region A.
            float (*vof)[132] = (float (*)[132])(smem + L_A);
            #pragma unroll 1
            for (int half = 0; half < 2; ++half) {
                #pragma unroll 2
                for (int nn = 0; nn < 8; ++nn) {
                    const int orow = (half * 8 + nn) * 16 + col;
                    const bf16x8* bp = (const bf16x8*)(wo + (size_t)orow * 256 + quad * 8);
                    bf16x8 bb[8];
                    #pragma unroll
                    for (int ks = 0; ks < 8; ++ks) bb[ks] = bp[ks * 4];
                    f32x4 acc = {0.f, 0.f, 0.f, 0.f};
                    #pragma unroll
                    for (int ks = 0; ks < 8; ++ks)
                        acc = __builtin_amdgcn_mfma_f32_16x16x32_bf16(af[ks], bb[ks], acc, 0, 0, 0);
                    const float bias = bf2f(pb[OFF_BOUT + orow]);
                    #pragma unroll
                    for (int rg = 0; rg < 4; ++rg)
                        vof[wave * 16 + quad * 4 + rg][nn * 16 + col] = acc[rg] + bias;
                }
                const int row = wave * 16 + (lane >> 2), l4 = lane & 3;
                const size_t gb = ((size_t)((b * 128 + hw * 8 + (row >> 3)) * 128
                                  + ww * 8 + (row & 7))) * 256 + (size_t)(half * 128);
                #pragma unroll
                for (int e = 0; e < 8; ++e) {
                    float4 vv = *(const float4*)&vof[row][e * 16 + l4 * 4];
                    *(float4*)((float*)outv + gb + e * 16 + l4 * 4) = vv;
                }
            }
        }
    }
}

// ---------------------------------------------------------------------------
extern "C" void kernel_launch(void* const* d_in, const int* in_sizes, int n_in,
                              void* d_out, int out_size, void* d_ws, size_t ws_size,
                              hipStream_t stream)
{
    const void* x    = d_in[0];
    const void* r    = d_in[1];
    const void* lnxw = d_in[2];
    const void* lnxb = d_in[3];
    const void* lnrw = d_in[4];
    const void* lnrb = d_in[5];
    const void* wqkv = d_in[6];
    const void* bqkv = d_in[7];
    const void* wout = d_in[8];
    const void* bout = d_in[9];

    ushort* pb = (ushort*)d_ws;   // 264192 bf16 elements = 516 KB

    kParams<<<1032, 256, 0, stream>>>(x, lnxw, lnxb, lnrw, lnrb,
                                      wqkv, bqkv, wout, bout, pb);

    (void)hipFuncSetAttribute((const void*)kMain,
                              hipFuncAttributeMaxDynamicSharedMemorySize, LDS_TOTAL);
    kMain<<<2048, 256, LDS_TOTAL, stream>>>(x, r, pb, d_out);
}

// Round 4
// 598.980 us; speedup vs baseline: 1.3393x; 1.3356x over previous
//
#include <hip/hip_runtime.h>
#include <math.h>

typedef unsigned int uint;
typedef unsigned short ushort;
typedef short bf16x8 __attribute__((ext_vector_type(8)));
typedef float f32x4 __attribute__((ext_vector_type(4)));

#define EPSV 1e-5f
#define SCALE 0.17677669529663687f   // 1/sqrt(32)

// param buffer offsets (bf16 elements) inside d_ws
#define OFF_WQKV 0
#define OFF_WOUT 196608
#define OFF_BQKV 262144
#define OFF_BOUT 262912
#define OFF_LNXW 263168
#define OFF_LNXB 263424
#define OFF_LNRW 263680
#define OFF_LNRB 263936

// LDS plan (138240 B -> 1 block/CU). Channel-split projection: each weight row
// is loaded by exactly ONE wave per block (4x fewer L2 reads, 1:4 load:MFMA).
//   ax  ushort[64][264] @ 0       LN(x)        (dead after proj -> f32 out stage)
//   ar  ushort[64][264] @ 33792   LN(r)        (dead after proj -> f32 out stage)
//   qh  ushort[64][72]  @ 67584   per-group q  [tok][gch]
//   kh  ushort[64][72]  @ 76800   per-group k  [tok][gch]
//   vT  ushort[64][72]  @ 86016   per-group v  [gch][tok]
//   ao  ushort[64][264] @ 95232   attention out accum [tok][ch]
//   Pw  4x ushort[16][72] @ 129024  per-wave P scratch
#define L_AX 0
#define L_AR 33792
#define L_QH 67584
#define L_KH 76800
#define L_VT 86016
#define L_AO 95232
#define L_PW 129024
#define LDS_TOTAL 138240

__device__ __forceinline__ float bf2f(ushort u) {
    union { float f; uint i; } z; z.i = ((uint)u) << 16; return z.f;
}
__device__ __forceinline__ ushort f2bf(float f) {
    union { float f; uint i; } z; z.f = f;
    uint i = z.i;
    return (ushort)((i + 0x7FFFu + ((i >> 16) & 1u)) >> 16);
}
__device__ __forceinline__ uint pack2(float a, float b) {
    return (uint)f2bf(a) | ((uint)f2bf(b) << 16);
}

// wave-parallel f32 detection: one load per lane + ballot
__device__ __forceinline__ bool detect_f32_wave(const uint* __restrict__ xw, int lane) {
    const uint e = (xw[lane] >> 7) & 0xFFu;
    const int pred = (e >= 0x60u && e <= 0x8Au) ? 1 : 0;
    const unsigned long long m = __ballot(pred);
    return __popcll(m) < 32;
}

// ---------------------------------------------------------------------------
// Param conversion.
// ---------------------------------------------------------------------------
__global__ __launch_bounds__(256) void kParams(
    const void* __restrict__ x,
    const void* __restrict__ lnxw, const void* __restrict__ lnxb,
    const void* __restrict__ lnrw, const void* __restrict__ lnrb,
    const void* __restrict__ wqkv, const void* __restrict__ bqkv,
    const void* __restrict__ wout, const void* __restrict__ bout,
    ushort* __restrict__ pb)
{
    const bool f32 = detect_f32_wave((const uint*)x, threadIdx.x & 63);
    const int blk = blockIdx.x, tid = threadIdx.x;
    const void* src; int si, doff;
    if (blk < 768)        { src = wqkv; si = blk * 256 + tid;          doff = OFF_WQKV; }
    else if (blk < 1024)  { src = wout; si = (blk - 768) * 256 + tid;  doff = OFF_WOUT; }
    else if (blk < 1027)  { src = bqkv; si = (blk - 1024) * 256 + tid; doff = OFF_BQKV; }
    else if (blk == 1027) { src = bout; si = tid; doff = OFF_BOUT; }
    else if (blk == 1028) { src = lnxw; si = tid; doff = OFF_LNXW; }
    else if (blk == 1029) { src = lnxb; si = tid; doff = OFF_LNXB; }
    else if (blk == 1030) { src = lnrw; si = tid; doff = OFF_LNRW; }
    else                  { src = lnrb; si = tid; doff = OFF_LNRB; }
    pb[doff + si] = f32 ? f2bf(((const float*)src)[si]) : ((const ushort*)src)[si];
}

// ---------------------------------------------------------------------------
// Load one 16-row weight B-tile (8 bf16x8 fragments) for this lane.
// ---------------------------------------------------------------------------
__device__ __forceinline__ void loadB(const ushort* __restrict__ wbase, int wrow,
                                      int quad, bf16x8 (&bb)[8])
{
    const bf16x8* bp = (const bf16x8*)(wbase + (size_t)wrow * 256 + quad * 8);
    #pragma unroll
    for (int ks = 0; ks < 8; ++ks) bb[ks] = bp[ks * 4];
}

// ---------------------------------------------------------------------------
// One projection task t (0..11): mat = t>>2 (0=q,1=k,2=v), sub-tile = t&3.
// Computes 16 output channels x all 64 tokens; A-frags read from LDS.
// ---------------------------------------------------------------------------
__device__ __forceinline__ void compT(
    const ushort* __restrict__ pb, char* __restrict__ smem,
    int t, int g, int col, int quad, const bf16x8 (&bb)[8])
{
    const int mat = t >> 2, sub = t & 3;
    const int wrow = mat * 256 + g * 64 + sub * 16 + col;
    const float bias = bf2f(pb[OFF_BQKV + wrow]);
    const ushort (*A)[264] = (const ushort (*)[264])(smem + (mat == 0 ? L_AX : L_AR));

    if (mat < 2) {
        ushort (*dst)[72] = (ushort (*)[72])(smem + (mat == 0 ? L_QH : L_KH));
        const float scl = (mat == 0) ? SCALE : 1.f;
        #pragma unroll
        for (int at = 0; at < 4; ++at) {
            f32x4 acc = {0.f, 0.f, 0.f, 0.f};
            #pragma unroll
            for (int ks = 0; ks < 8; ++ks) {
                const bf16x8 aF = *(const bf16x8*)&A[at * 16 + col][ks * 32 + quad * 8];
                acc = __builtin_amdgcn_mfma_f32_16x16x32_bf16(aF, bb[ks], acc, 0, 0, 0);
            }
            #pragma unroll
            for (int rg = 0; rg < 4; ++rg)
                dst[at * 16 + quad * 4 + rg][sub * 16 + col] = f2bf((acc[rg] + bias) * scl);
        }
    } else {
        ushort (*vT)[72] = (ushort (*)[72])(smem + L_VT);
        #pragma unroll
        for (int at = 0; at < 4; ++at) {
            f32x4 acc = {0.f, 0.f, 0.f, 0.f};
            #pragma unroll
            for (int ks = 0; ks < 8; ++ks) {
                const bf16x8 aF = *(const bf16x8*)&A[at * 16 + col][ks * 32 + quad * 8];
                acc = __builtin_amdgcn_mfma_f32_16x16x32_bf16(aF, bb[ks], acc, 0, 0, 0);
            }
            uint2 pv;
            pv.x = pack2(acc[0] + bias, acc[1] + bias);
            pv.y = pack2(acc[2] + bias, acc[3] + bias);
            *(uint2*)&vT[sub * 16 + col][at * 16 + quad * 4] = pv;
        }
    }
}

// ---------------------------------------------------------------------------
// Projection for head-group g (heads 2g, 2g+1): 12 tasks, 3 per wave,
// with next-task B prefetch to hide L2 latency under MFMA.
// ---------------------------------------------------------------------------
__device__ __forceinline__ void projGroup(
    const ushort* __restrict__ pb, char* __restrict__ smem,
    int g, int wave, int col, int quad)
{
    const ushort* wq = pb + OFF_WQKV;
    const int t0 = wave * 3, t1 = t0 + 1, t2 = t0 + 2;
    const int w0 = (t0 >> 2) * 256 + g * 64 + (t0 & 3) * 16 + col;
    const int w1 = (t1 >> 2) * 256 + g * 64 + (t1 & 3) * 16 + col;
    const int w2 = (t2 >> 2) * 256 + g * 64 + (t2 & 3) * 16 + col;

    bf16x8 p0[8], p1[8];
    loadB(wq, w0, quad, p0);
    loadB(wq, w1, quad, p1);
    compT(pb, smem, t0, g, col, quad, p0);
    loadB(wq, w2, quad, p0);
    compT(pb, smem, t1, g, col, quad, p1);
    compT(pb, smem, t2, g, col, quad, p0);
}

// ---------------------------------------------------------------------------
// Attention for head-group g: wave owns tokens [wave*16, +16), both heads.
// QK^T (K=32), wave-parallel softmax, PV; output -> ao (wave-local rows).
// ---------------------------------------------------------------------------
__device__ __forceinline__ void attGroup(
    char* __restrict__ smem, ushort (*Pw)[72],
    int g, int wave, int col, int quad)
{
    const ushort (*qh)[72] = (const ushort (*)[72])(smem + L_QH);
    const ushort (*kh)[72] = (const ushort (*)[72])(smem + L_KH);
    const ushort (*vT)[72] = (const ushort (*)[72])(smem + L_VT);
    ushort (*ao)[264] = (ushort (*)[264])(smem + L_AO);

    #pragma unroll
    for (int hs = 0; hs < 2; ++hs) {
        const bf16x8 qa = *(const bf16x8*)&qh[wave * 16 + col][hs * 32 + quad * 8];
        f32x4 s[4];
        #pragma unroll
        for (int nt = 0; nt < 4; ++nt) {
            const bf16x8 kb = *(const bf16x8*)&kh[nt * 16 + col][hs * 32 + quad * 8];
            f32x4 z = {0.f, 0.f, 0.f, 0.f};
            s[nt] = __builtin_amdgcn_mfma_f32_16x16x32_bf16(qa, kb, z, 0, 0, 0);
        }
        #pragma unroll
        for (int rg = 0; rg < 4; ++rg) {
            float m = fmaxf(fmaxf(s[0][rg], s[1][rg]), fmaxf(s[2][rg], s[3][rg]));
            m = fmaxf(m, __shfl_xor(m, 1));
            m = fmaxf(m, __shfl_xor(m, 2));
            m = fmaxf(m, __shfl_xor(m, 4));
            m = fmaxf(m, __shfl_xor(m, 8));
            float p0 = __expf(s[0][rg] - m);
            float p1 = __expf(s[1][rg] - m);
            float p2 = __expf(s[2][rg] - m);
            float p3 = __expf(s[3][rg] - m);
            float sm = p0 + p1 + p2 + p3;
            sm += __shfl_xor(sm, 1);
            sm += __shfl_xor(sm, 2);
            sm += __shfl_xor(sm, 4);
            sm += __shfl_xor(sm, 8);
            const float inv = 1.f / sm;
            s[0][rg] = p0 * inv; s[1][rg] = p1 * inv;
            s[2][rg] = p2 * inv; s[3][rg] = p3 * inv;
        }
        #pragma unroll
        for (int nt = 0; nt < 4; ++nt)
            #pragma unroll
            for (int rg = 0; rg < 4; ++rg)
                Pw[quad * 4 + rg][nt * 16 + col] = f2bf(s[nt][rg]);
        const bf16x8 pa0 = *(const bf16x8*)&Pw[col][quad * 8];
        const bf16x8 pa1 = *(const bf16x8*)&Pw[col][32 + quad * 8];
        #pragma unroll
        for (int n2 = 0; n2 < 2; ++n2) {
            const bf16x8 bv0 = *(const bf16x8*)&vT[hs * 32 + n2 * 16 + col][quad * 8];
            const bf16x8 bv1 = *(const bf16x8*)&vT[hs * 32 + n2 * 16 + col][32 + quad * 8];
            f32x4 acc = {0.f, 0.f, 0.f, 0.f};
            acc = __builtin_amdgcn_mfma_f32_16x16x32_bf16(pa0, bv0, acc, 0, 0, 0);
            acc = __builtin_amdgcn_mfma_f32_16x16x32_bf16(pa1, bv1, acc, 0, 0, 0);
            #pragma unroll
            for (int rg = 0; rg < 4; ++rg)
                ao[wave * 16 + quad * 4 + rg][(g * 2 + hs) * 32 + n2 * 16 + col] =
                    f2bf(acc[rg]);
        }
    }
}

// ---------------------------------------------------------------------------
// Fused per-window kernel. Channel-split projections, 1 block/CU.
// ---------------------------------------------------------------------------
__global__ __launch_bounds__(256, 1) void kMain(
    const void* __restrict__ xv, const void* __restrict__ rv,
    const ushort* __restrict__ pb, void* __restrict__ outv)
{
    extern __shared__ char smem[];
    const int tid = threadIdx.x;
    const int lane = tid & 63, wave = tid >> 6;
    const int col = lane & 15, quad = lane >> 4;
    const bool f32 = detect_f32_wave((const uint*)xv, lane);
    const int w = blockIdx.x, b = w >> 8, hw = (w >> 4) & 15, ww = w & 15;
    ushort (*Pw)[72] = (ushort (*)[72])(smem + L_PW + wave * 2304);

    // ---- Phase 1: LN x -> ax, LN r -> ar. 8 threads/token, 2 passes each. ----
    {
        const int l8 = tid & 7, trow = tid >> 3;
        #pragma unroll 1
        for (int t = 0; t < 2; ++t) {
            const void* src = t ? rv : xv;
            const ushort* lw = pb + (t ? OFF_LNRW : OFF_LNXW);
            const ushort* lb = pb + (t ? OFF_LNRB : OFF_LNXB);
            ushort (*dst)[264] = (ushort (*)[264])(smem + (t ? L_AR : L_AX));
            #pragma unroll 1
            for (int p = 0; p < 2; ++p) {
                const int row = p * 32 + trow;
                const int pi = row >> 3, pj = row & 7;
                const size_t gidx = ((size_t)((b * 128 + hw * 8 + pi) * 128 + ww * 8 + pj)) * 256
                                  + (size_t)(l8 * 32);
                float vals[32];
                if (f32) {
                    const float4* g = (const float4*)((const float*)src + gidx);
                    #pragma unroll
                    for (int it = 0; it < 8; ++it) {
                        float4 q = g[it];
                        vals[it * 4 + 0] = q.x; vals[it * 4 + 1] = q.y;
                        vals[it * 4 + 2] = q.z; vals[it * 4 + 3] = q.w;
                    }
                } else {
                    const uint4* g = (const uint4*)((const ushort*)src + gidx);
                    #pragma unroll
                    for (int it = 0; it < 4; ++it) {
                        uint4 q = g[it];
                        uint u[4] = {q.x, q.y, q.z, q.w};
                        #pragma unroll
                        for (int e = 0; e < 4; ++e) {
                            vals[it * 8 + e * 2]     = bf2f((ushort)(u[e] & 0xffff));
                            vals[it * 8 + e * 2 + 1] = bf2f((ushort)(u[e] >> 16));
                        }
                    }
                }
                float s0 = 0.f, s1 = 0.f;
                #pragma unroll
                for (int c = 0; c < 32; ++c) { s0 += vals[c]; s1 += vals[c] * vals[c]; }
                s0 += __shfl_xor(s0, 1); s1 += __shfl_xor(s1, 1);
                s0 += __shfl_xor(s0, 2); s1 += __shfl_xor(s1, 2);
                s0 += __shfl_xor(s0, 4); s1 += __shfl_xor(s1, 4);
                const float mean = s0 * (1.f / 256.f);
                const float var  = s1 * (1.f / 256.f) - mean * mean;
                const float rs   = rsqrtf(var + EPSV);
                #pragma unroll
                for (int c = 0; c < 32; c += 2) {
                    const int ch = l8 * 32 + c;
                    float a0 = (vals[c]     - mean) * rs * bf2f(lw[ch])     + bf2f(lb[ch]);
                    float a1 = (vals[c + 1] - mean) * rs * bf2f(lw[ch + 1]) + bf2f(lb[ch + 1]);
                    *(uint*)&dst[row][ch] = pack2(a0, a1);
                }
            }
        }
        __syncthreads();
    }

    // ---- Phase 2+3: per-head-group proj (channel-split) + attention.
    //      Group order rotated by blockIdx to de-hotspot L2. ----
    #pragma unroll 1
    for (int gg = 0; gg < 4; ++gg) {
        const int g = (gg + w) & 3;
        projGroup(pb, smem, g, wave, col, quad);
        __syncthreads();
        attGroup(smem, Pw, g, wave, col, quad);
        __syncthreads();
    }

    // ---- Phase 4: out-projection (channel-split: wave w -> out ch [w*64,+64))
    //      staged into the dead ax/ar region, then coalesced dump. ----
    {
        const ushort* wo = pb + OFF_WOUT;
        const ushort (*ao)[264] = (const ushort (*)[264])(smem + L_AO);
        float  (*sf)[264] = (float  (*)[264])(smem + L_AX);   // f32 stage (67584 B)
        ushort (*sh)[264] = (ushort (*)[264])(smem + L_AX);   // bf16 stage

        bf16x8 p0[8], p1[8];
        const int r0 = wave * 64 + col;
        loadB(wo, r0,      quad, p0);
        loadB(wo, r0 + 16, quad, p1);
        #pragma unroll
        for (int sub = 0; sub < 4; ++sub) {
            const int orow = wave * 64 + sub * 16 + col;
            const float bias = bf2f(pb[OFF_BOUT + orow]);
            // consume current tile, prefetch tile sub+2
            const bf16x8 (&bb)[8] = (sub & 1) ? p1 : p0;
            #pragma unroll
            for (int at = 0; at < 4; ++at) {
                f32x4 acc = {0.f, 0.f, 0.f, 0.f};
                #pragma unroll
                for (int ks = 0; ks < 8; ++ks) {
                    const bf16x8 aF = *(const bf16x8*)&ao[at * 16 + col][ks * 32 + quad * 8];
                    acc = __builtin_amdgcn_mfma_f32_16x16x32_bf16(aF, bb[ks], acc, 0, 0, 0);
                }
                if (f32) {
                    #pragma unroll
                    for (int rg = 0; rg < 4; ++rg)
                        sf[at * 16 + quad * 4 + rg][orow] = acc[rg] + bias;
                } else {
                    #pragma unroll
                    for (int rg = 0; rg < 4; ++rg)
                        sh[at * 16 + quad * 4 + rg][orow] = f2bf(acc[rg] + bias);
                }
            }
            if (sub == 0) loadB(wo, r0 + 32, quad, p0);
            if (sub == 1) loadB(wo, r0 + 48, quad, p1);
        }
        __syncthreads();

        const int row = wave * 16 + (lane >> 2), l4 = lane & 3;
        const size_t gb = ((size_t)((b * 128 + hw * 8 + (row >> 3)) * 128
                          + ww * 8 + (row & 7))) * 256;
        if (f32) {
            #pragma unroll
            for (int e = 0; e < 16; ++e) {
                float4 vv = *(const float4*)&sf[row][e * 16 + l4 * 4];
                *(float4*)((float*)outv + gb + e * 16 + l4 * 4) = vv;
            }
        } else {
            #pragma unroll
            for (int e = 0; e < 8; ++e) {
                uint4 vvv = *(const uint4*)&sh[row][l4 * 64 + e * 8];
                *(uint4*)((ushort*)outv + gb + (size_t)(l4 * 64 + e * 8)) = vvv;
            }
        }
    }
}

// ---------------------------------------------------------------------------
extern "C" void kernel_launch(void* const* d_in, const int* in_sizes, int n_in,
                              void* d_out, int out_size, void* d_ws, size_t ws_size,
                              hipStream_t stream)
{
    const void* x    = d_in[0];
    const void* r    = d_in[1];
    const void* lnxw = d_in[2];
    const void* lnxb = d_in[3];
    const void* lnrw = d_in[4];
    const void* lnrb = d_in[5];
    const void* wqkv = d_in[6];
    const void* bqkv = d_in[7];
    const void* wout = d_in[8];
    const void* bout = d_in[9];

    ushort* pb = (ushort*)d_ws;   // 264192 bf16 elements = 516 KB

    kParams<<<1032, 256, 0, stream>>>(x, lnxw, lnxb, lnrw, lnrb,
                                      wqkv, bqkv, wout, bout, pb);

    (void)hipFuncSetAttribute((const void*)kMain,
                              hipFuncAttributeMaxDynamicSharedMemorySize, LDS_TOTAL);
    kMain<<<2048, 256, LDS_TOTAL, stream>>>(x, r, pb, d_out);
}

// Round 5
// 537.309 us; speedup vs baseline: 1.4930x; 1.1148x over previous
//
#include <hip/hip_runtime.h>
#include <math.h>

typedef unsigned int uint;
typedef unsigned short ushort;
typedef short bf16x8 __attribute__((ext_vector_type(8)));
typedef float f32x4 __attribute__((ext_vector_type(4)));

#define EPSV 1e-5f
#define SCALE 0.17677669529663687f   // 1/sqrt(32)

// param buffer offsets (bf16 elements) inside d_ws
#define OFF_WQKV 0
#define OFF_WOUT 196608
#define OFF_BQKV 262144
#define OFF_BOUT 262912
#define OFF_LNXW 263168
#define OFF_LNXB 263424
#define OFF_LNRW 263680
#define OFF_LNRB 263936

// LDS plan (70656 B -> 2 blocks/CU = 2 waves/SIMD).
//   ar  ushort[64][264] @ 0      LN(x) temp -> LN(r) persistent -> ao -> dead
//   qh  ushort[64][72]  @ 33792  per-group q [tok][gch]
//   kh  ushort[64][72]  @ 43008  per-group k [tok][gch]
//   vT  ushort[64][72]  @ 52224  per-group v [gch][tok]
//   Pw  4x ushort[16][72] @ 61440  per-wave P scratch
//   phase-4 staging overlays qh..Pw (36864 B) at 33792
#define L_AR 0
#define L_QH 33792
#define L_KH 43008
#define L_VT 52224
#define L_PW 61440
#define L_ST 33792
#define LDS_TOTAL 70656

__device__ __forceinline__ float bf2f(ushort u) {
    union { float f; uint i; } z; z.i = ((uint)u) << 16; return z.f;
}
__device__ __forceinline__ ushort f2bf(float f) {
    union { float f; uint i; } z; z.f = f;
    uint i = z.i;
    return (ushort)((i + 0x7FFFu + ((i >> 16) & 1u)) >> 16);
}
__device__ __forceinline__ uint pack2(float a, float b) {
    return (uint)f2bf(a) | ((uint)f2bf(b) << 16);
}

// wave-parallel f32 detection: one load per lane + ballot
__device__ __forceinline__ bool detect_f32_wave(const uint* __restrict__ xw, int lane) {
    const uint e = (xw[lane] >> 7) & 0xFFu;
    const int pred = (e >= 0x60u && e <= 0x8Au) ? 1 : 0;
    const unsigned long long m = __ballot(pred);
    return __popcll(m) < 32;
}

// ---------------------------------------------------------------------------
// Param conversion.
// ---------------------------------------------------------------------------
__global__ __launch_bounds__(256) void kParams(
    const void* __restrict__ x,
    const void* __restrict__ lnxw, const void* __restrict__ lnxb,
    const void* __restrict__ lnrw, const void* __restrict__ lnrb,
    const void* __restrict__ wqkv, const void* __restrict__ bqkv,
    const void* __restrict__ wout, const void* __restrict__ bout,
    ushort* __restrict__ pb)
{
    const bool f32 = detect_f32_wave((const uint*)x, threadIdx.x & 63);
    const int blk = blockIdx.x, tid = threadIdx.x;
    const void* src; int si, doff;
    if (blk < 768)        { src = wqkv; si = blk * 256 + tid;          doff = OFF_WQKV; }
    else if (blk < 1024)  { src = wout; si = (blk - 768) * 256 + tid;  doff = OFF_WOUT; }
    else if (blk < 1027)  { src = bqkv; si = (blk - 1024) * 256 + tid; doff = OFF_BQKV; }
    else if (blk == 1027) { src = bout; si = tid; doff = OFF_BOUT; }
    else if (blk == 1028) { src = lnxw; si = tid; doff = OFF_LNXW; }
    else if (blk == 1029) { src = lnxb; si = tid; doff = OFF_LNXB; }
    else if (blk == 1030) { src = lnrw; si = tid; doff = OFF_LNRW; }
    else                  { src = lnrb; si = tid; doff = OFF_LNRB; }
    pb[doff + si] = f32 ? f2bf(((const float*)src)[si]) : ((const ushort*)src)[si];
}

// ---------------------------------------------------------------------------
// Load one 16-row weight B-tile (8 bf16x8 fragments) for this lane.
// ---------------------------------------------------------------------------
__device__ __forceinline__ void loadB(const ushort* __restrict__ wbase, int wrow,
                                      int quad, bf16x8 (&bb)[8])
{
    const bf16x8* bp = (const bf16x8*)(wbase + (size_t)wrow * 256 + quad * 8);
    #pragma unroll
    for (int ks = 0; ks < 8; ++ks) bb[ks] = bp[ks * 4];
}

// ---------------------------------------------------------------------------
// q sub-tile (token-split): wave's 16 tokens x 16 group-channels, A from regs.
// ---------------------------------------------------------------------------
__device__ __forceinline__ void compQ(
    const ushort* __restrict__ pb, char* __restrict__ smem,
    int g, int sub, const bf16x8 (&ax)[8], const bf16x8 (&bb)[8],
    int wave, int col, int quad)
{
    ushort (*qh)[72] = (ushort (*)[72])(smem + L_QH);
    f32x4 acc = {0.f, 0.f, 0.f, 0.f};
    #pragma unroll
    for (int ks = 0; ks < 8; ++ks)
        acc = __builtin_amdgcn_mfma_f32_16x16x32_bf16(ax[ks], bb[ks], acc, 0, 0, 0);
    const int wrow = g * 64 + sub * 16 + col;
    const float bias = bf2f(pb[OFF_BQKV + wrow]);
    #pragma unroll
    for (int rg = 0; rg < 4; ++rg)
        qh[wave * 16 + quad * 4 + rg][sub * 16 + col] = f2bf((acc[rg] + bias) * SCALE);
}

// ---------------------------------------------------------------------------
// k/v sub-tile (channel-split): 16 channels x all 64 tokens, A from ar LDS.
// ---------------------------------------------------------------------------
__device__ __forceinline__ void compKV(
    const ushort* __restrict__ pb, char* __restrict__ smem,
    int g, int mat, int sub, const bf16x8 (&bb)[8],
    int col, int quad)
{
    const ushort (*ar)[264] = (const ushort (*)[264])(smem + L_AR);
    const int wrow = mat * 256 + g * 64 + sub * 16 + col;
    const float bias = bf2f(pb[OFF_BQKV + wrow]);
    if (mat == 1) {
        ushort (*kh)[72] = (ushort (*)[72])(smem + L_KH);
        #pragma unroll
        for (int at = 0; at < 4; ++at) {
            f32x4 acc = {0.f, 0.f, 0.f, 0.f};
            #pragma unroll
            for (int ks = 0; ks < 8; ++ks) {
                const bf16x8 aF = *(const bf16x8*)&ar[at * 16 + col][ks * 32 + quad * 8];
                acc = __builtin_amdgcn_mfma_f32_16x16x32_bf16(aF, bb[ks], acc, 0, 0, 0);
            }
            #pragma unroll
            for (int rg = 0; rg < 4; ++rg)
                kh[at * 16 + quad * 4 + rg][sub * 16 + col] = f2bf(acc[rg] + bias);
        }
    } else {
        ushort (*vT)[72] = (ushort (*)[72])(smem + L_VT);
        #pragma unroll
        for (int at = 0; at < 4; ++at) {
            f32x4 acc = {0.f, 0.f, 0.f, 0.f};
            #pragma unroll
            for (int ks = 0; ks < 8; ++ks) {
                const bf16x8 aF = *(const bf16x8*)&ar[at * 16 + col][ks * 32 + quad * 8];
                acc = __builtin_amdgcn_mfma_f32_16x16x32_bf16(aF, bb[ks], acc, 0, 0, 0);
            }
            uint2 pv;
            pv.x = pack2(acc[0] + bias, acc[1] + bias);
            pv.y = pack2(acc[2] + bias, acc[3] + bias);
            *(uint2*)&vT[sub * 16 + col][at * 16 + quad * 4] = pv;
        }
    }
}

// ---------------------------------------------------------------------------
// Projection for head-group g: q token-split (ax regs), k/v channel-split.
// 2-deep weight-tile prefetch throughout.
// ---------------------------------------------------------------------------
__device__ __forceinline__ void projGroup(
    const ushort* __restrict__ pb, char* __restrict__ smem,
    const bf16x8 (&ax)[8], int g, int wave, int col, int quad)
{
    const ushort* wq = pb + OFF_WQKV;
    const int mat = 1 + (wave >> 1);            // waves 0,1 -> k ; waves 2,3 -> v
    const int sb0 = (wave & 1) * 2, sb1 = sb0 + 1;

    bf16x8 p0[8], p1[8];
    loadB(wq, g * 64 + col,      quad, p0);
    loadB(wq, g * 64 + 16 + col, quad, p1);
    compQ(pb, smem, g, 0, ax, p0, wave, col, quad);
    loadB(wq, g * 64 + 32 + col, quad, p0);
    compQ(pb, smem, g, 1, ax, p1, wave, col, quad);
    loadB(wq, g * 64 + 48 + col, quad, p1);
    compQ(pb, smem, g, 2, ax, p0, wave, col, quad);
    loadB(wq, mat * 256 + g * 64 + sb0 * 16 + col, quad, p0);
    compQ(pb, smem, g, 3, ax, p1, wave, col, quad);
    loadB(wq, mat * 256 + g * 64 + sb1 * 16 + col, quad, p1);
    compKV(pb, smem, g, mat, sb0, p0, col, quad);
    compKV(pb, smem, g, mat, sb1, p1, col, quad);
}

// ---------------------------------------------------------------------------
// Attention for head-group g: wave owns tokens [wave*16,+16), both heads.
// QK^T (K=32), wave-parallel softmax, PV -> aopk registers (C-layout packed).
// ---------------------------------------------------------------------------
__device__ __forceinline__ void attGroup(
    char* __restrict__ smem, ushort (*Pw)[72], uint (&aopk)[16][2],
    int g, int wave, int col, int quad)
{
    const ushort (*qh)[72] = (const ushort (*)[72])(smem + L_QH);
    const ushort (*kh)[72] = (const ushort (*)[72])(smem + L_KH);
    const ushort (*vT)[72] = (const ushort (*)[72])(smem + L_VT);

    #pragma unroll
    for (int hs = 0; hs < 2; ++hs) {
        const bf16x8 qa = *(const bf16x8*)&qh[wave * 16 + col][hs * 32 + quad * 8];
        f32x4 s[4];
        #pragma unroll
        for (int nt = 0; nt < 4; ++nt) {
            const bf16x8 kb = *(const bf16x8*)&kh[nt * 16 + col][hs * 32 + quad * 8];
            f32x4 z = {0.f, 0.f, 0.f, 0.f};
            s[nt] = __builtin_amdgcn_mfma_f32_16x16x32_bf16(qa, kb, z, 0, 0, 0);
        }
        #pragma unroll
        for (int rg = 0; rg < 4; ++rg) {
            float m = fmaxf(fmaxf(s[0][rg], s[1][rg]), fmaxf(s[2][rg], s[3][rg]));
            m = fmaxf(m, __shfl_xor(m, 1));
            m = fmaxf(m, __shfl_xor(m, 2));
            m = fmaxf(m, __shfl_xor(m, 4));
            m = fmaxf(m, __shfl_xor(m, 8));
            float p0 = __expf(s[0][rg] - m);
            float p1 = __expf(s[1][rg] - m);
            float p2 = __expf(s[2][rg] - m);
            float p3 = __expf(s[3][rg] - m);
            float sm = p0 + p1 + p2 + p3;
            sm += __shfl_xor(sm, 1);
            sm += __shfl_xor(sm, 2);
            sm += __shfl_xor(sm, 4);
            sm += __shfl_xor(sm, 8);
            const float inv = 1.f / sm;
            s[0][rg] = p0 * inv; s[1][rg] = p1 * inv;
            s[2][rg] = p2 * inv; s[3][rg] = p3 * inv;
        }
        #pragma unroll
        for (int nt = 0; nt < 4; ++nt)
            #pragma unroll
            for (int rg = 0; rg < 4; ++rg)
                Pw[quad * 4 + rg][nt * 16 + col] = f2bf(s[nt][rg]);
        const bf16x8 pa0 = *(const bf16x8*)&Pw[col][quad * 8];
        const bf16x8 pa1 = *(const bf16x8*)&Pw[col][32 + quad * 8];
        #pragma unroll
        for (int n2 = 0; n2 < 2; ++n2) {
            const bf16x8 bv0 = *(const bf16x8*)&vT[hs * 32 + n2 * 16 + col][quad * 8];
            const bf16x8 bv1 = *(const bf16x8*)&vT[hs * 32 + n2 * 16 + col][32 + quad * 8];
            f32x4 acc = {0.f, 0.f, 0.f, 0.f};
            acc = __builtin_amdgcn_mfma_f32_16x16x32_bf16(pa0, bv0, acc, 0, 0, 0);
            acc = __builtin_amdgcn_mfma_f32_16x16x32_bf16(pa1, bv1, acc, 0, 0, 0);
            aopk[g * 4 + hs * 2 + n2][0] = pack2(acc[0], acc[1]);
            aopk[g * 4 + hs * 2 + n2][1] = pack2(acc[2], acc[3]);
        }
    }
}

// ---------------------------------------------------------------------------
// Fused per-window kernel: 2 blocks/CU, hybrid token/channel-split.
// ---------------------------------------------------------------------------
__global__ __launch_bounds__(256, 2) void kMain(
    const void* __restrict__ xv, const void* __restrict__ rv,
    const ushort* __restrict__ pb, void* __restrict__ outv)
{
    extern __shared__ char smem[];
    const int tid = threadIdx.x;
    const int lane = tid & 63, wave = tid >> 6;
    const int col = lane & 15, quad = lane >> 4;
    const bool f32 = detect_f32_wave((const uint*)xv, lane);
    const int w = blockIdx.x, b = w >> 8, hw = (w >> 4) & 15, ww = w & 15;
    ushort (*Pw)[72] = (ushort (*)[72])(smem + L_PW + wave * 2304);
    ushort (*AR)[264] = (ushort (*)[264])(smem + L_AR);

    // ---- Phase 1: LN(x) -> region (read ax frags to regs) ; LN(r) -> region ----
    bf16x8 ax[8];
    {
        const int l8 = tid & 7, trow = tid >> 3;
        #pragma unroll 1
        for (int t = 0; t < 2; ++t) {
            const void* src = t ? rv : xv;
            const ushort* lw = pb + (t ? OFF_LNRW : OFF_LNXW);
            const ushort* lb = pb + (t ? OFF_LNRB : OFF_LNXB);
            #pragma unroll 1
            for (int p = 0; p < 2; ++p) {
                const int row = p * 32 + trow;
                const int pi = row >> 3, pj = row & 7;
                const size_t gidx = ((size_t)((b * 128 + hw * 8 + pi) * 128 + ww * 8 + pj)) * 256
                                  + (size_t)(l8 * 32);
                float vals[32];
                if (f32) {
                    const float4* g = (const float4*)((const float*)src + gidx);
                    #pragma unroll
                    for (int it = 0; it < 8; ++it) {
                        float4 q = g[it];
                        vals[it * 4 + 0] = q.x; vals[it * 4 + 1] = q.y;
                        vals[it * 4 + 2] = q.z; vals[it * 4 + 3] = q.w;
                    }
                } else {
                    const uint4* g = (const uint4*)((const ushort*)src + gidx);
                    #pragma unroll
                    for (int it = 0; it < 4; ++it) {
                        uint4 q = g[it];
                        uint u[4] = {q.x, q.y, q.z, q.w};
                        #pragma unroll
                        for (int e = 0; e < 4; ++e) {
                            vals[it * 8 + e * 2]     = bf2f((ushort)(u[e] & 0xffff));
                            vals[it * 8 + e * 2 + 1] = bf2f((ushort)(u[e] >> 16));
                        }
                    }
                }
                float s0 = 0.f, s1 = 0.f;
                #pragma unroll
                for (int c = 0; c < 32; ++c) { s0 += vals[c]; s1 += vals[c] * vals[c]; }
                s0 += __shfl_xor(s0, 1); s1 += __shfl_xor(s1, 1);
                s0 += __shfl_xor(s0, 2); s1 += __shfl_xor(s1, 2);
                s0 += __shfl_xor(s0, 4); s1 += __shfl_xor(s1, 4);
                const float mean = s0 * (1.f / 256.f);
                const float var  = s1 * (1.f / 256.f) - mean * mean;
                const float rs   = rsqrtf(var + EPSV);
                #pragma unroll
                for (int c = 0; c < 32; c += 2) {
                    const int ch = l8 * 32 + c;
                    float a0 = (vals[c]     - mean) * rs * bf2f(lw[ch])     + bf2f(lb[ch]);
                    float a1 = (vals[c + 1] - mean) * rs * bf2f(lw[ch + 1]) + bf2f(lb[ch + 1]);
                    *(uint*)&AR[row][ch] = pack2(a0, a1);
                }
            }
            __syncthreads();
            if (t == 0) {
                #pragma unroll
                for (int ks = 0; ks < 8; ++ks)
                    ax[ks] = *(const bf16x8*)&AR[wave * 16 + col][ks * 32 + quad * 8];
                __syncthreads();   // region free for LN(r)
            }
        }
    }

    // ---- Phase 2+3: per-group proj + attention (unrolled: aopk in regs) ----
    uint aopk[16][2];
    #pragma unroll
    for (int g = 0; g < 4; ++g) {
        projGroup(pb, smem, ax, g, wave, col, quad);
        __syncthreads();
        attGroup(smem, Pw, aopk, g, wave, col, quad);
        __syncthreads();
    }

    // ---- Phase 4: aopk -> ao image in dead ar region; channel-split out-proj ----
    {
        ushort (*ao)[264] = AR;
        #pragma unroll
        for (int t = 0; t < 16; ++t) {
            const uint lo = aopk[t][0], hi = aopk[t][1];
            ao[wave * 16 + quad * 4 + 0][t * 16 + col] = (ushort)(lo & 0xffff);
            ao[wave * 16 + quad * 4 + 1][t * 16 + col] = (ushort)(lo >> 16);
            ao[wave * 16 + quad * 4 + 2][t * 16 + col] = (ushort)(hi & 0xffff);
            ao[wave * 16 + quad * 4 + 3][t * 16 + col] = (ushort)(hi >> 16);
        }
        __syncthreads();

        const ushort* wo = pb + OFF_WOUT;
        if (!f32) {
            ushort (*sh)[264] = (ushort (*)[264])(smem + L_ST);
            bf16x8 p0[8], p1[8];
            const int r0 = wave * 64 + col;
            loadB(wo, r0,      quad, p0);
            loadB(wo, r0 + 16, quad, p1);
            #pragma unroll
            for (int sub = 0; sub < 4; ++sub) {
                const int orow = wave * 64 + sub * 16 + col;
                const float bias = bf2f(pb[OFF_BOUT + orow]);
                const bf16x8 (&bb)[8] = (sub & 1) ? p1 : p0;
                #pragma unroll
                for (int at = 0; at < 4; ++at) {
                    f32x4 acc = {0.f, 0.f, 0.f, 0.f};
                    #pragma unroll
                    for (int ks = 0; ks < 8; ++ks) {
                        const bf16x8 aF = *(const bf16x8*)&ao[at * 16 + col][ks * 32 + quad * 8];
                        acc = __builtin_amdgcn_mfma_f32_16x16x32_bf16(aF, bb[ks], acc, 0, 0, 0);
                    }
                    #pragma unroll
                    for (int rg = 0; rg < 4; ++rg)
                        sh[at * 16 + quad * 4 + rg][orow] = f2bf(acc[rg] + bias);
                }
                if (sub == 0) loadB(wo, r0 + 32, quad, p0);
                if (sub == 1) loadB(wo, r0 + 48, quad, p1);
            }
            __syncthreads();

            const int row = wave * 16 + (lane >> 2), l4 = lane & 3;
            const size_t gb = ((size_t)((b * 128 + hw * 8 + (row >> 3)) * 128
                              + ww * 8 + (row & 7))) * 256;
            #pragma unroll
            for (int e = 0; e < 8; ++e) {
                uint4 vvv = *(const uint4*)&sh[row][l4 * 64 + e * 8];
                *(uint4*)((ushort*)outv + gb + (size_t)(l4 * 64 + e * 8)) = vvv;
            }
        } else {
            // f32 output: two half-channel passes staged as f32 [64][132].
            float (*sf)[132] = (float (*)[132])(smem + L_ST);
            #pragma unroll 1
            for (int half = 0; half < 2; ++half) {
                if (half) __syncthreads();   // protect stage from previous dump
                bf16x8 p0[8], p1[8];
                const int r0 = half * 128 + wave * 32 + col;
                loadB(wo, r0,      quad, p0);
                loadB(wo, r0 + 16, quad, p1);
                #pragma unroll
                for (int sub2 = 0; sub2 < 2; ++sub2) {
                    const int orow = half * 128 + wave * 32 + sub2 * 16 + col;
                    const float bias = bf2f(pb[OFF_BOUT + orow]);
                    const bf16x8 (&bb)[8] = sub2 ? p1 : p0;
                    #pragma unroll
                    for (int at = 0; at < 4; ++at) {
                        f32x4 acc = {0.f, 0.f, 0.f, 0.f};
                        #pragma unroll
                        for (int ks = 0; ks < 8; ++ks) {
                            const bf16x8 aF = *(const bf16x8*)&ao[at * 16 + col][ks * 32 + quad * 8];
                            acc = __builtin_amdgcn_mfma_f32_16x16x32_bf16(aF, bb[ks], acc, 0, 0, 0);
                        }
                        #pragma unroll
                        for (int rg = 0; rg < 4; ++rg)
                            sf[at * 16 + quad * 4 + rg][wave * 32 + sub2 * 16 + col] =
                                acc[rg] + bias;
                    }
                }
                __syncthreads();
                const int row = wave * 16 + (lane >> 2), l4 = lane & 3;
                const size_t gb = ((size_t)((b * 128 + hw * 8 + (row >> 3)) * 128
                                  + ww * 8 + (row & 7))) * 256 + (size_t)(half * 128);
                #pragma unroll
                for (int e = 0; e < 8; ++e) {
                    float4 vv = *(const float4*)&sf[row][e * 16 + l4 * 4];
                    *(float4*)((float*)outv + gb + e * 16 + l4 * 4) = vv;
                }
            }
        }
    }
}

// ---------------------------------------------------------------------------
extern "C" void kernel_launch(void* const* d_in, const int* in_sizes, int n_in,
                              void* d_out, int out_size, void* d_ws, size_t ws_size,
                              hipStream_t stream)
{
    const void* x    = d_in[0];
    const void* r    = d_in[1];
    const void* lnxw = d_in[2];
    const void* lnxb = d_in[3];
    const void* lnrw = d_in[4];
    const void* lnrb = d_in[5];
    const void* wqkv = d_in[6];
    const void* bqkv = d_in[7];
    const void* wout = d_in[8];
    const void* bout = d_in[9];

    ushort* pb = (ushort*)d_ws;   // 264192 bf16 elements = 516 KB

    kParams<<<1032, 256, 0, stream>>>(x, lnxw, lnxb, lnrw, lnrb,
                                      wqkv, bqkv, wout, bout, pb);

    (void)hipFuncSetAttribute((const void*)kMain,
                              hipFuncAttributeMaxDynamicSharedMemorySize, LDS_TOTAL);
    kMain<<<2048, 256, LDS_TOTAL, stream>>>(x, r, pb, d_out);
}